// Round 2
// baseline (219.038 us; speedup 1.0000x reference)
//
#include <hip/hip_runtime.h>
#include <hip/hip_bf16.h>
#include <stdint.h>

#define N_NODES 2048
#define WORDS   32          // 2048/64 bitset words per row
#define LABELS  16
#define FILTERS 16
#define FNODES  8
#define MAX_EGO 128
#define WL_LEVELS 4

__device__ __forceinline__ unsigned mixu(unsigned h) {
    h ^= h >> 16; h *= 0x7FEB352Du;
    h ^= h >> 15; h *= 0x846CA68Bu;
    h ^= h >> 16;
    return h;
}

// Set adjacency bits from directed edge list (already contains both directions;
// we set both anyway to mirror the reference's symmetrization).
__global__ void build_adj_kernel(const int* __restrict__ ei, int E2,
                                 unsigned long long* __restrict__ A) {
    int e = blockIdx.x * blockDim.x + threadIdx.x;
    if (e >= E2) return;
    int s = ei[e], d = ei[E2 + e];
    atomicOr(&A[(size_t)s * WORDS + (d >> 6)], 1ull << (d & 63));
    atomicOr(&A[(size_t)d * WORDS + (s >> 6)], 1ull << (s & 63));
}

// r1 = I | A
__global__ void reach_init_kernel(const unsigned long long* __restrict__ A,
                                  unsigned long long* __restrict__ r) {
    int idx = blockIdx.x * blockDim.x + threadIdx.x;
    if (idx >= N_NODES * WORDS) return;
    int i = idx >> 5;   // WORDS == 32
    int w = idx & 31;
    unsigned long long v = A[idx];
    if ((i >> 6) == w) v |= 1ull << (i & 63);
    r[idx] = v;
}

// rout[i] = rin[i] | OR_{v in N(i)} rin[v]   (one more hop)
__global__ void reach_step_kernel(const unsigned long long* __restrict__ A,
                                  const unsigned long long* __restrict__ rin,
                                  unsigned long long* __restrict__ rout) {
    int i = blockIdx.x;
    __shared__ unsigned long long arow[WORDS];
    int tid = threadIdx.x;
    if (tid < WORDS) arow[tid] = A[(size_t)i * WORDS + tid];
    __syncthreads();
    if (tid < WORDS) {
        unsigned long long acc = rin[(size_t)i * WORDS + tid];
        for (int w = 0; w < WORDS; ++w) {
            unsigned long long bits = arow[w];
            while (bits) {
                int b = __ffsll(bits) - 1;
                bits &= bits - 1;
                int v = (w << 6) + b;
                acc |= rin[(size_t)v * WORDS + tid];
            }
        }
        rout[(size_t)i * WORDS + tid] = acc;
    }
}

// One thread per filter graph: CC mask, labels, all 4 WL hash levels, self_f.
__global__ void filters_kernel(const float* __restrict__ A, const float* __restrict__ X,
                               unsigned* __restrict__ hf, unsigned* __restrict__ fmaskb,
                               float* __restrict__ selff) {
    int f = threadIdx.x;
    if (f >= FILTERS) return;
    const float* Af = A + (size_t)f * FNODES * FNODES;
    unsigned row[FNODES];
    for (int m = 0; m < FNODES; ++m) {
        unsigned r = 0;
        for (int j = 0; j < FNODES; ++j)
            if (Af[m * FNODES + j] > 0.f) r |= 1u << j;
        row[m] = r;
    }
    const float* Xf = X + (size_t)f * FNODES * LABELS;
    unsigned lab[FNODES];
    for (int m = 0; m < FNODES; ++m) {
        const float* xr = Xf + m * LABELS;
        float best = xr[0]; int bi = 0;
        for (int c = 1; c < LABELS; ++c) { float v = xr[c]; if (v > best) { best = v; bi = c; } }
        lab[m] = (unsigned)(bi + 1);
    }
    // largest connected component via min-label propagation (exactly FNODES sync iters)
    int lbl[FNODES];
    for (int m = 0; m < FNODES; ++m) lbl[m] = m;
    for (int it = 0; it < FNODES; ++it) {
        int nb[FNODES];
        for (int m = 0; m < FNODES; ++m) {
            int mn = FNODES;
            for (int j = 0; j < FNODES; ++j)
                if ((row[m] >> j) & 1) mn = min(mn, lbl[j]);
            nb[m] = mn;
        }
        for (int m = 0; m < FNODES; ++m) lbl[m] = min(lbl[m], nb[m]);
    }
    int cnt[FNODES];
    for (int m = 0; m < FNODES; ++m) {
        int c = 0;
        for (int j = 0; j < FNODES; ++j) c += (lbl[j] == lbl[m]);
        cnt[m] = c;
    }
    int best = 0;
    for (int m = 1; m < FNODES; ++m) if (cnt[m] > cnt[best]) best = m;
    unsigned fm = 0;
    for (int m = 0; m < FNODES; ++m) if (lbl[m] == lbl[best]) fm |= 1u << m;
    fmaskb[f] = fm;
    unsigned brow[FNODES];
    for (int m = 0; m < FNODES; ++m) brow[m] = ((fm >> m) & 1) ? (row[m] & fm) : 0u;
    unsigned h[FNODES];
    for (int m = 0; m < FNODES; ++m) h[m] = mixu(lab[m]);
    float sf = 0.f;
    for (int t = 0; t < WL_LEVELS; ++t) {
        if (t > 0) {
            unsigned mx[FNODES], nh[FNODES];
            for (int m = 0; m < FNODES; ++m) mx[m] = mixu(h[m]);
            for (int m = 0; m < FNODES; ++m) {
                unsigned msg = 0;
                for (int j = 0; j < FNODES; ++j)
                    if ((brow[m] >> j) & 1) msg += mx[j];
                nh[m] = mixu(h[m] * 0x9E3779B1u + msg);
            }
            for (int m = 0; m < FNODES; ++m) h[m] = nh[m];
        }
        for (int m = 0; m < FNODES; ++m)
            hf[t * FILTERS * FNODES + f * FNODES + m] = h[m];
        int c = 0;
        for (int m = 0; m < FNODES; ++m) if ((fm >> m) & 1)
            for (int j = 0; j < FNODES; ++j) if ((fm >> j) & 1) c += (h[m] == h[j]);
        sf += (float)c;
    }
    selff[f] = sf;
}

// One block per seed node.
__global__ void __launch_bounds__(128)
ego_kernel(const float* __restrict__ x,
           const unsigned long long* __restrict__ Adense,
           const unsigned long long* __restrict__ reach,
           const unsigned* __restrict__ hf, const unsigned* __restrict__ fmaskb,
           const float* __restrict__ selff, float* __restrict__ out) {
    int i   = blockIdx.x;
    int tid = threadIdx.x;

    __shared__ unsigned members[MAX_EGO];
    __shared__ unsigned h[MAX_EGO];
    __shared__ unsigned mixed_s[MAX_EGO];
    __shared__ unsigned long long adj[MAX_EGO][2];
    __shared__ unsigned hf_s[WL_LEVELS * FILTERS * FNODES];
    __shared__ unsigned fmb[FILTERS];
    __shared__ unsigned cross_s[FILTERS];
    __shared__ unsigned selfe_s;
    __shared__ int Scnt;

    for (int t = tid; t < WL_LEVELS * FILTERS * FNODES; t += blockDim.x) hf_s[t] = hf[t];
    if (tid < FILTERS) { fmb[tid] = fmaskb[tid]; cross_s[tid] = 0; }

    // Member set: seed + up to 127 smallest-index reachable nodes (order irrelevant).
    if (tid == 0) {
        selfe_s = 0;
        int cnt = 0;
        members[cnt++] = (unsigned)i;
        const unsigned long long* rrow = reach + (size_t)i * WORDS;
        for (int w = 0; w < WORDS && cnt < MAX_EGO; ++w) {
            unsigned long long bits = rrow[w];
            while (bits && cnt < MAX_EGO) {
                int b = __ffsll(bits) - 1;
                bits &= bits - 1;
                int j = (w << 6) + b;
                if (j != i) members[cnt++] = (unsigned)j;
            }
        }
        Scnt = cnt;
    }
    __syncthreads();
    int S = Scnt;

    // Initial labels + ego adjacency bit-rows.
    if (tid < S) {
        unsigned m = members[tid];
        const float* xr = x + (size_t)m * LABELS;
        float best = xr[0]; int bi = 0;
        #pragma unroll
        for (int c = 1; c < LABELS; ++c) { float v = xr[c]; if (v > best) { best = v; bi = c; } }
        h[tid] = mixu((unsigned)(bi + 1));
        const unsigned long long* arow = Adense + (size_t)m * WORDS;
        unsigned long long a0 = 0, a1 = 0;
        for (int l = 0; l < S; ++l) {
            unsigned ml = members[l];
            unsigned long long wv = arow[ml >> 6];
            if ((wv >> (ml & 63)) & 1ull) {
                if (l < 64) a0 |= 1ull << l; else a1 |= 1ull << (l - 64);
            }
        }
        adj[tid][0] = a0; adj[tid][1] = a1;
    }
    __syncthreads();

    unsigned crossReg[FILTERS];
    #pragma unroll
    for (int f = 0; f < FILTERS; ++f) crossReg[f] = 0;
    unsigned selfeReg = 0;

    for (int t = 0; t < WL_LEVELS; ++t) {
        if (t > 0) {
            if (tid < S) mixed_s[tid] = mixu(h[tid]);
            __syncthreads();
            unsigned hnew = 0;
            if (tid < S) {
                unsigned msg = 0;
                unsigned long long bits = adj[tid][0];
                while (bits) { int l = __ffsll(bits) - 1; bits &= bits - 1; msg += mixed_s[l]; }
                bits = adj[tid][1];
                while (bits) { int l = __ffsll(bits) - 1; bits &= bits - 1; msg += mixed_s[64 + l]; }
                hnew = mixu(h[tid] * 0x9E3779B1u + msg);
            }
            __syncthreads();
            if (tid < S) h[tid] = hnew;
            __syncthreads();
        }
        if (tid < S) {
            unsigned hv = h[tid];
            const unsigned* hrow = &hf_s[t * FILTERS * FNODES];
            #pragma unroll
            for (int f = 0; f < FILTERS; ++f) {
                unsigned fm = fmb[f];
                unsigned c = 0;
                #pragma unroll
                for (int m = 0; m < FNODES; ++m)
                    c += (unsigned)((hv == hrow[f * FNODES + m]) & ((fm >> m) & 1u));
                crossReg[f] += c;
            }
            unsigned ce = 0;
            for (int l = 0; l < S; ++l) ce += (unsigned)(h[l] == hv);
            selfeReg += ce;
        }
        __syncthreads();
    }

    // Reduce: wave shuffle then one LDS atomic per wave.
    #pragma unroll
    for (int f = 0; f < FILTERS; ++f) {
        unsigned v = crossReg[f];
        for (int o = 32; o > 0; o >>= 1) v += __shfl_down(v, o, 64);
        if ((tid & 63) == 0) atomicAdd(&cross_s[f], v);
    }
    {
        unsigned v = selfeReg;
        for (int o = 32; o > 0; o >>= 1) v += __shfl_down(v, o, 64);
        if ((tid & 63) == 0) atomicAdd(&selfe_s, v);
    }
    __syncthreads();

    if (tid < FILTERS) {
        float se = (float)selfe_s;
        float sf = selff[tid];
        float denom = sqrtf(se * sf);
        float v = (denom > 0.f) ? ((float)cross_s[tid] / denom) : 0.f;
        out[(size_t)i * FILTERS + tid] = v;
    }
}

extern "C" void kernel_launch(void* const* d_in, const int* in_sizes, int n_in,
                              void* d_out, int out_size, void* d_ws, size_t ws_size,
                              hipStream_t stream) {
    const float* x  = (const float*)d_in[0];
    const int*   ei = (const int*)d_in[1];
    // d_in[2] = batch (unused: single graph)
    const float* A  = (const float*)d_in[3];
    const float* X  = (const float*)d_in[4];
    float* out = (float*)d_out;
    int E2 = in_sizes[1] / 2;   // directed edge count (both directions present)

    char* ws = (char*)d_ws;
    const size_t ADJ_BYTES = (size_t)N_NODES * WORDS * sizeof(unsigned long long); // 512 KB
    unsigned long long* Adense = (unsigned long long*)(ws);
    unsigned long long* r0     = (unsigned long long*)(ws + ADJ_BYTES);
    unsigned long long* r1     = (unsigned long long*)(ws + 2 * ADJ_BYTES);
    unsigned* hf      = (unsigned*)(ws + 3 * ADJ_BYTES);
    unsigned* fmaskb  = (unsigned*)(ws + 3 * ADJ_BYTES + 4096);
    float*    selff   = (float*)  (ws + 3 * ADJ_BYTES + 4096 + 256);

    hipMemsetAsync(Adense, 0, ADJ_BYTES, stream);
    build_adj_kernel<<<(E2 + 255) / 256, 256, 0, stream>>>(ei, E2, Adense);
    reach_init_kernel<<<(N_NODES * WORDS + 255) / 256, 256, 0, stream>>>(Adense, r0); // dist<=1
    reach_step_kernel<<<N_NODES, 64, 0, stream>>>(Adense, r0, r1);                    // dist<=2
    reach_step_kernel<<<N_NODES, 64, 0, stream>>>(Adense, r1, r0);                    // dist<=3
    filters_kernel<<<1, 64, 0, stream>>>(A, X, hf, fmaskb, selff);
    ego_kernel<<<N_NODES, 128, 0, stream>>>(x, Adense, r0, hf, fmaskb, selff, out);
}

// Round 3
// 172.741 us; speedup vs baseline: 1.2680x; 1.2680x over previous
//
#include <hip/hip_runtime.h>
#include <hip/hip_bf16.h>
#include <stdint.h>

#define N_NODES 2048
#define WORDS   32          // 2048/64 bitset words per row
#define LABELS  16
#define FILTERS 16
#define FNODES  8
#define MAX_EGO 128
#define WL_LEVELS 4

typedef unsigned long long u64;

__device__ __forceinline__ unsigned mixu(unsigned h) {
    h ^= h >> 16; h *= 0x7FEB352Du;
    h ^= h >> 15; h *= 0x846CA68Bu;
    h ^= h >> 16;
    return h;
}

__global__ void build_adj_kernel(const int* __restrict__ ei, int E2,
                                 u64* __restrict__ A) {
    int e = blockIdx.x * blockDim.x + threadIdx.x;
    if (e >= E2) return;
    int s = ei[e], d = ei[E2 + e];
    atomicOr(&A[(size_t)s * WORDS + (d >> 6)], 1ull << (d & 63));
    atomicOr(&A[(size_t)d * WORDS + (s >> 6)], 1ull << (s & 63));
}

// rout[i] = rin[i] | OR_{v in A(i)} rin[v], with optional implicit diagonal on rin.
// Block = 64 threads = 2 nodes (full wave utilization), lane w = word index.
__global__ void reach_step_kernel(const u64* __restrict__ A,
                                  const u64* __restrict__ rin,
                                  u64* __restrict__ rout, int with_diag) {
    int g = threadIdx.x >> 5;
    int w = threadIdx.x & 31;
    int i = blockIdx.x * 2 + g;
    __shared__ u64 arow[2][WORDS];
    arow[g][w] = A[(size_t)i * WORDS + w];
    __syncthreads();
    u64 acc = rin[(size_t)i * WORDS + w];
    if (with_diag && (i >> 6) == w) acc |= 1ull << (i & 63);
    for (int w2 = 0; w2 < WORDS; ++w2) {
        u64 bits = arow[g][w2];
        while (bits) {
            int b = __ffsll(bits) - 1;
            bits &= bits - 1;
            int v = (w2 << 6) + b;
            u64 rv = rin[(size_t)v * WORDS + w];
            if (with_diag && (v >> 6) == w) rv |= 1ull << (v & 63);
            acc |= rv;
        }
    }
    rout[(size_t)i * WORDS + w] = acc;
}

// One thread per filter graph: CC mask, labels, all 4 WL hash levels, self_f.
__global__ void filters_kernel(const float* __restrict__ A, const float* __restrict__ X,
                               unsigned* __restrict__ hf, unsigned* __restrict__ fmaskb,
                               float* __restrict__ selff) {
    int f = threadIdx.x;
    if (f >= FILTERS) return;
    const float* Af = A + (size_t)f * FNODES * FNODES;
    unsigned row[FNODES];
    for (int m = 0; m < FNODES; ++m) {
        unsigned r = 0;
        for (int j = 0; j < FNODES; ++j)
            if (Af[m * FNODES + j] > 0.f) r |= 1u << j;
        row[m] = r;
    }
    const float* Xf = X + (size_t)f * FNODES * LABELS;
    unsigned lab[FNODES];
    for (int m = 0; m < FNODES; ++m) {
        const float* xr = Xf + m * LABELS;
        float best = xr[0]; int bi = 0;
        for (int c = 1; c < LABELS; ++c) { float v = xr[c]; if (v > best) { best = v; bi = c; } }
        lab[m] = (unsigned)(bi + 1);
    }
    int lbl[FNODES];
    for (int m = 0; m < FNODES; ++m) lbl[m] = m;
    for (int it = 0; it < FNODES; ++it) {
        int nb[FNODES];
        for (int m = 0; m < FNODES; ++m) {
            int mn = FNODES;
            for (int j = 0; j < FNODES; ++j)
                if ((row[m] >> j) & 1) mn = min(mn, lbl[j]);
            nb[m] = mn;
        }
        for (int m = 0; m < FNODES; ++m) lbl[m] = min(lbl[m], nb[m]);
    }
    int cnt[FNODES];
    for (int m = 0; m < FNODES; ++m) {
        int c = 0;
        for (int j = 0; j < FNODES; ++j) c += (lbl[j] == lbl[m]);
        cnt[m] = c;
    }
    int best = 0;
    for (int m = 1; m < FNODES; ++m) if (cnt[m] > cnt[best]) best = m;
    unsigned fm = 0;
    for (int m = 0; m < FNODES; ++m) if (lbl[m] == lbl[best]) fm |= 1u << m;
    fmaskb[f] = fm;
    unsigned brow[FNODES];
    for (int m = 0; m < FNODES; ++m) brow[m] = ((fm >> m) & 1) ? (row[m] & fm) : 0u;
    unsigned h[FNODES];
    for (int m = 0; m < FNODES; ++m) h[m] = mixu(lab[m]);
    float sf = 0.f;
    for (int t = 0; t < WL_LEVELS; ++t) {
        if (t > 0) {
            unsigned mx[FNODES], nh[FNODES];
            for (int m = 0; m < FNODES; ++m) mx[m] = mixu(h[m]);
            for (int m = 0; m < FNODES; ++m) {
                unsigned msg = 0;
                for (int j = 0; j < FNODES; ++j)
                    if ((brow[m] >> j) & 1) msg += mx[j];
                nh[m] = mixu(h[m] * 0x9E3779B1u + msg);
            }
            for (int m = 0; m < FNODES; ++m) h[m] = nh[m];
        }
        for (int m = 0; m < FNODES; ++m)
            hf[t * FILTERS * FNODES + f * FNODES + m] = h[m];
        int c = 0;
        for (int m = 0; m < FNODES; ++m) if ((fm >> m) & 1)
            for (int j = 0; j < FNODES; ++j) if ((fm >> j) & 1) c += (h[m] == h[j]);
        sf += (float)c;
    }
    selff[f] = sf;
}

// One block (128 threads) per seed node.
__global__ void __launch_bounds__(128)
ego_kernel(const float* __restrict__ x,
           const u64* __restrict__ Adense,
           const u64* __restrict__ reach,
           const unsigned* __restrict__ hf, const unsigned* __restrict__ fmaskb,
           const float* __restrict__ selff, float* __restrict__ out) {
    int i   = blockIdx.x;
    int tid = threadIdx.x;

    __shared__ u64 mmask[WORDS];            // member-set bitset over node ids
    __shared__ unsigned pfx[WORDS];         // exclusive popcount prefix of mmask
    __shared__ unsigned members[MAX_EGO];   // slot -> node id
    __shared__ unsigned h[MAX_EGO];
    __shared__ unsigned mixed_s[MAX_EGO];
    __shared__ unsigned adjs[MAX_EGO][5];   // 128-bit compact adjacency (4 used + pad)
    __shared__ unsigned hf_s[WL_LEVELS * FILTERS * FNODES];
    __shared__ unsigned fmb[FILTERS];
    __shared__ unsigned cross_s[FILTERS];
    __shared__ unsigned selfe_s;
    __shared__ int Scnt;

    for (int t = tid; t < WL_LEVELS * FILTERS * FNODES; t += 128) hf_s[t] = hf[t];
    if (tid < FILTERS) { fmb[tid] = fmaskb[tid]; cross_s[tid] = 0; }
    if (tid == 0) selfe_s = 0;
    if (tid < MAX_EGO) { adjs[tid][0] = 0; adjs[tid][1] = 0; adjs[tid][2] = 0; adjs[tid][3] = 0; }

    // ---- member mask: seed + first 127 reachable (by ascending node id) ----
    if (tid < WORDS) {
        int w = tid;
        u64 v = reach[(size_t)i * WORDS + w];
        int seedw = i >> 6;
        u64 seedbit = 1ull << (i & 63);
        if (w == seedw) v &= ~seedbit;          // handle seed separately
        int pc = __popcll(v);
        // inclusive scan of pc over 32 lanes
        int incl = pc;
        for (int d = 1; d < 32; d <<= 1) {
            int t2 = __shfl_up(incl, d, 32);
            if (w >= d) incl += t2;
        }
        int excl = incl - pc;
        const int keep = MAX_EGO - 1;           // 127 non-seed members max
        if (excl >= keep) {
            v = 0;
        } else {
            int allow = keep - excl;
            while (pc > allow) {                 // drop highest-index bits
                v &= ~(1ull << (63 - __clzll(v)));
                --pc;
            }
        }
        if (w == seedw) v |= seedbit;
        mmask[w] = v;
        int pc2 = __popcll(v);
        int incl2 = pc2;
        for (int d = 1; d < 32; d <<= 1) {
            int t2 = __shfl_up(incl2, d, 32);
            if (w >= d) incl2 += t2;
        }
        pfx[w] = (unsigned)(incl2 - pc2);
        if (w == 31) Scnt = incl2;
        // enumerate members into slots
        u64 vv = v;
        int r = 0;
        while (vv) {
            int b = __ffsll(vv) - 1;
            vv &= vv - 1;
            members[incl2 - pc2 + r] = (unsigned)((w << 6) + b);
            ++r;
        }
    }
    __syncthreads();
    int S = Scnt;

    // ---- initial WL labels (argmax over 16 floats, first-max tie-break) ----
    if (tid < S) {
        unsigned m = members[tid];
        const float* xr = x + (size_t)m * LABELS;
        float best = xr[0]; int bi = 0;
        #pragma unroll
        for (int c = 1; c < LABELS; ++c) { float v = xr[c]; if (v > best) { best = v; bi = c; } }
        h[tid] = mixu((unsigned)(bi + 1));
    }

    // ---- compact ego adjacency: row(slot t) = compact(Adense[member_t] & mmask) ----
    {
        int g = tid >> 5, lane = tid & 31;
        for (int t = g; t < S; t += 4) {
            unsigned mt = members[t];                       // LDS broadcast
            u64 v = Adense[(size_t)mt * WORDS + lane] & mmask[lane];
            unsigned base = pfx[lane];
            u64 mw = mmask[lane];
            while (v) {
                int b = __ffsll(v) - 1;
                v &= v - 1;
                int slot = (int)base + __popcll(mw & ((1ull << b) - 1));
                atomicOr(&adjs[t][slot >> 5], 1u << (slot & 31));
            }
        }
    }
    __syncthreads();

    unsigned crossReg[FILTERS];
    #pragma unroll
    for (int f = 0; f < FILTERS; ++f) crossReg[f] = 0;
    unsigned selfeReg = 0;

    for (int t = 0; t < WL_LEVELS; ++t) {
        if (t > 0) {
            if (tid < S) mixed_s[tid] = mixu(h[tid]);
            __syncthreads();
            unsigned hnew = 0;
            if (tid < S) {
                unsigned msg = 0;
                #pragma unroll
                for (int w = 0; w < 4; ++w) {
                    unsigned bits = adjs[tid][w];
                    while (bits) {
                        int l = __ffs(bits) - 1;
                        bits &= bits - 1;
                        msg += mixed_s[(w << 5) + l];
                    }
                }
                hnew = mixu(h[tid] * 0x9E3779B1u + msg);
            }
            __syncthreads();
            if (tid < S) h[tid] = hnew;
            __syncthreads();
        }
        if (tid < S) {
            unsigned hv = h[tid];
            const unsigned* hrow = &hf_s[t * FILTERS * FNODES];
            #pragma unroll
            for (int f = 0; f < FILTERS; ++f) {
                unsigned fm = fmb[f];
                unsigned c = 0;
                #pragma unroll
                for (int m = 0; m < FNODES; ++m)
                    c += (unsigned)((hv == hrow[f * FNODES + m]) & ((fm >> m) & 1u));
                crossReg[f] += c;
            }
            unsigned ce = 0;
            for (int l = 0; l < S; ++l) ce += (unsigned)(h[l] == hv);
            selfeReg += ce;
        }
        __syncthreads();
    }

    // ---- reduce: wave shuffle then one LDS atomic per wave ----
    #pragma unroll
    for (int f = 0; f < FILTERS; ++f) {
        unsigned v = crossReg[f];
        for (int o = 32; o > 0; o >>= 1) v += __shfl_down(v, o, 64);
        if ((tid & 63) == 0) atomicAdd(&cross_s[f], v);
    }
    {
        unsigned v = selfeReg;
        for (int o = 32; o > 0; o >>= 1) v += __shfl_down(v, o, 64);
        if ((tid & 63) == 0) atomicAdd(&selfe_s, v);
    }
    __syncthreads();

    if (tid < FILTERS) {
        float se = (float)selfe_s;
        float sf = selff[tid];
        float denom = sqrtf(se * sf);
        float v = (denom > 0.f) ? ((float)cross_s[tid] / denom) : 0.f;
        out[(size_t)i * FILTERS + tid] = v;
    }
}

extern "C" void kernel_launch(void* const* d_in, const int* in_sizes, int n_in,
                              void* d_out, int out_size, void* d_ws, size_t ws_size,
                              hipStream_t stream) {
    const float* x  = (const float*)d_in[0];
    const int*   ei = (const int*)d_in[1];
    // d_in[2] = batch (unused: single graph)
    const float* A  = (const float*)d_in[3];
    const float* X  = (const float*)d_in[4];
    float* out = (float*)d_out;
    int E2 = in_sizes[1] / 2;   // directed edge count (both directions present)

    char* ws = (char*)d_ws;
    const size_t ADJ_BYTES = (size_t)N_NODES * WORDS * sizeof(u64); // 512 KB
    u64* Adense = (u64*)(ws);
    u64* r1     = (u64*)(ws + ADJ_BYTES);
    u64* r3     = (u64*)(ws + 2 * ADJ_BYTES);
    unsigned* hf      = (unsigned*)(ws + 3 * ADJ_BYTES);
    unsigned* fmaskb  = (unsigned*)(ws + 3 * ADJ_BYTES + 4096);
    float*    selff   = (float*)  (ws + 3 * ADJ_BYTES + 4096 + 256);

    hipMemsetAsync(Adense, 0, ADJ_BYTES, stream);
    build_adj_kernel<<<(E2 + 255) / 256, 256, 0, stream>>>(ei, E2, Adense);
    // r1 = (I|A)^2, r3 = (I|A)^3  (implicit diagonal in pass 1)
    reach_step_kernel<<<N_NODES / 2, 64, 0, stream>>>(Adense, Adense, r1, 1);
    reach_step_kernel<<<N_NODES / 2, 64, 0, stream>>>(Adense, r1, r3, 0);
    filters_kernel<<<1, 64, 0, stream>>>(A, X, hf, fmaskb, selff);
    ego_kernel<<<N_NODES, 128, 0, stream>>>(x, Adense, r3, hf, fmaskb, selff, out);
}

// Round 4
// 163.835 us; speedup vs baseline: 1.3369x; 1.0544x over previous
//
#include <hip/hip_runtime.h>
#include <hip/hip_bf16.h>
#include <stdint.h>

#define N_NODES 2048
#define WORDS   32          // 2048/64 bitset words per row
#define LABELS  16
#define FILTERS 16
#define FNODES  8
#define MAX_EGO 128
#define WL_LEVELS 4
#define SPB     2           // seeds (egonets) per block; 1 wave per seed

typedef unsigned long long u64;

__device__ __forceinline__ unsigned mixu(unsigned h) {
    h ^= h >> 16; h *= 0x7FEB352Du;
    h ^= h >> 15; h *= 0x846CA68Bu;
    h ^= h >> 16;
    return h;
}

__global__ void build_adj_kernel(const int* __restrict__ ei, int E2,
                                 u64* __restrict__ A) {
    int e = blockIdx.x * blockDim.x + threadIdx.x;
    if (e >= E2) return;
    int s = ei[e], d = ei[E2 + e];
    atomicOr(&A[(size_t)s * WORDS + (d >> 6)], 1ull << (d & 63));
    atomicOr(&A[(size_t)d * WORDS + (s >> 6)], 1ull << (s & 63));
}

// rout[i] = rin[i] | OR_{v in A(i)} rin[v], with implicit diagonal on rin.
__global__ void reach_step_kernel(const u64* __restrict__ A,
                                  const u64* __restrict__ rin,
                                  u64* __restrict__ rout, int with_diag) {
    int g = threadIdx.x >> 5;
    int w = threadIdx.x & 31;
    int i = blockIdx.x * 2 + g;
    __shared__ u64 arow[2][WORDS];
    arow[g][w] = A[(size_t)i * WORDS + w];
    __syncthreads();
    u64 acc = rin[(size_t)i * WORDS + w];
    if (with_diag && (i >> 6) == w) acc |= 1ull << (i & 63);
    for (int w2 = 0; w2 < WORDS; ++w2) {
        u64 bits = arow[g][w2];
        while (bits) {
            int b = __ffsll(bits) - 1;
            bits &= bits - 1;
            int v = (w2 << 6) + b;
            u64 rv = rin[(size_t)v * WORDS + w];
            if (with_diag && (v >> 6) == w) rv |= 1ull << (v & 63);
            acc |= rv;
        }
    }
    rout[(size_t)i * WORDS + w] = acc;
}

// One thread per filter graph: CC mask, labels, all 4 WL hash levels, self_f.
__global__ void filters_kernel(const float* __restrict__ A, const float* __restrict__ X,
                               unsigned* __restrict__ hf, unsigned* __restrict__ fmaskb,
                               float* __restrict__ selff) {
    int f = threadIdx.x;
    if (f >= FILTERS) return;
    const float* Af = A + (size_t)f * FNODES * FNODES;
    unsigned row[FNODES];
    for (int m = 0; m < FNODES; ++m) {
        unsigned r = 0;
        for (int j = 0; j < FNODES; ++j)
            if (Af[m * FNODES + j] > 0.f) r |= 1u << j;
        row[m] = r;
    }
    const float* Xf = X + (size_t)f * FNODES * LABELS;
    unsigned lab[FNODES];
    for (int m = 0; m < FNODES; ++m) {
        const float* xr = Xf + m * LABELS;
        float best = xr[0]; int bi = 0;
        for (int c = 1; c < LABELS; ++c) { float v = xr[c]; if (v > best) { best = v; bi = c; } }
        lab[m] = (unsigned)(bi + 1);
    }
    int lbl[FNODES];
    for (int m = 0; m < FNODES; ++m) lbl[m] = m;
    for (int it = 0; it < FNODES; ++it) {
        int nb[FNODES];
        for (int m = 0; m < FNODES; ++m) {
            int mn = FNODES;
            for (int j = 0; j < FNODES; ++j)
                if ((row[m] >> j) & 1) mn = min(mn, lbl[j]);
            nb[m] = mn;
        }
        for (int m = 0; m < FNODES; ++m) lbl[m] = min(lbl[m], nb[m]);
    }
    int cnt[FNODES];
    for (int m = 0; m < FNODES; ++m) {
        int c = 0;
        for (int j = 0; j < FNODES; ++j) c += (lbl[j] == lbl[m]);
        cnt[m] = c;
    }
    int best = 0;
    for (int m = 1; m < FNODES; ++m) if (cnt[m] > cnt[best]) best = m;
    unsigned fm = 0;
    for (int m = 0; m < FNODES; ++m) if (lbl[m] == lbl[best]) fm |= 1u << m;
    fmaskb[f] = fm;
    unsigned brow[FNODES];
    for (int m = 0; m < FNODES; ++m) brow[m] = ((fm >> m) & 1) ? (row[m] & fm) : 0u;
    unsigned h[FNODES];
    for (int m = 0; m < FNODES; ++m) h[m] = mixu(lab[m]);
    float sf = 0.f;
    for (int t = 0; t < WL_LEVELS; ++t) {
        if (t > 0) {
            unsigned mx[FNODES], nh[FNODES];
            for (int m = 0; m < FNODES; ++m) mx[m] = mixu(h[m]);
            for (int m = 0; m < FNODES; ++m) {
                unsigned msg = 0;
                for (int j = 0; j < FNODES; ++j)
                    if ((brow[m] >> j) & 1) msg += mx[j];
                nh[m] = mixu(h[m] * 0x9E3779B1u + msg);
            }
            for (int m = 0; m < FNODES; ++m) h[m] = nh[m];
        }
        for (int m = 0; m < FNODES; ++m)
            hf[t * FILTERS * FNODES + f * FNODES + m] = h[m];
        int c = 0;
        for (int m = 0; m < FNODES; ++m) if ((fm >> m) & 1)
            for (int j = 0; j < FNODES; ++j) if ((fm >> j) & 1) c += (h[m] == h[j]);
        sf += (float)c;
    }
    selff[f] = sf;
}

// One WAVE per seed node, SPB seeds per 128-thread block.
// Lane owns slots (lane) and (lane+64). Final hop of reachability computed inline.
__global__ void __launch_bounds__(128)
ego_kernel(const float* __restrict__ x,
           const u64* __restrict__ Adense,
           const u64* __restrict__ r2,
           const unsigned* __restrict__ hf, const unsigned* __restrict__ fmaskb,
           const float* __restrict__ selff, float* __restrict__ out) {
    const int wid  = threadIdx.x >> 6;     // local seed index (wave id)
    const int lane = threadIdx.x & 63;
    const int i    = blockIdx.x * SPB + wid;

    __shared__ u64 arow[SPB][WORDS];
    __shared__ u64 mmask[SPB][WORDS];
    __shared__ unsigned pfx[SPB][WORDS];
    __shared__ unsigned members[SPB][MAX_EGO];
    __shared__ unsigned h[SPB][MAX_EGO];
    __shared__ unsigned mixed[SPB][MAX_EGO];
    __shared__ __align__(16) unsigned adjs[SPB][MAX_EGO][4];
    __shared__ unsigned hf_s[WL_LEVELS * FILTERS * FNODES];
    __shared__ unsigned fmb[FILTERS];
    __shared__ unsigned cross_sh[SPB][FILTERS];
    __shared__ int Scnt[SPB];

    for (int t = threadIdx.x; t < WL_LEVELS * FILTERS * FNODES; t += 128) hf_s[t] = hf[t];
    if (threadIdx.x < FILTERS) fmb[threadIdx.x] = fmaskb[threadIdx.x];
    for (int t = threadIdx.x; t < SPB * MAX_EGO * 4; t += 128) ((unsigned*)adjs)[t] = 0;

    if (lane < WORDS) arow[wid][lane] = Adense[(size_t)i * WORDS + lane];
    __syncthreads();

    // ---- hop 3 + member mask: both half-waves compute word w = lane&31;
    //      neighbor set split by word-parity, merged via shfl_xor(32). ----
    {
        int w  = lane & 31;
        int hw = lane >> 5;
        u64 v = (hw == 0) ? r2[(size_t)i * WORDS + w] : 0ull;
        for (int w2 = hw; w2 < WORDS; w2 += 2) {
            u64 bits = arow[wid][w2];
            while (bits) {
                int b = __ffsll(bits) - 1;
                bits &= bits - 1;
                v |= r2[(size_t)((w2 << 6) + b) * WORDS + w];
            }
        }
        v |= __shfl_xor(v, 32, 64);           // both halves now hold full r3 word w
        // trim to seed + 127 smallest-index members (both halves run identically)
        int seedw = i >> 6;
        u64 seedbit = 1ull << (i & 63);
        if (w == seedw) v &= ~seedbit;
        int pc = __popcll(v);
        int incl = pc;
        for (int d = 1; d < 32; d <<= 1) {
            int t2 = __shfl_up(incl, d, 32);
            if (w >= d) incl += t2;
        }
        int excl = incl - pc;
        const int keep = MAX_EGO - 1;
        if (excl >= keep) {
            v = 0;
        } else {
            int allow = keep - excl;
            while (pc > allow) {
                v &= ~(1ull << (63 - __clzll(v)));
                --pc;
            }
        }
        if (w == seedw) v |= seedbit;
        mmask[wid][w] = v;
        int pc2 = __popcll(v);
        int incl2 = pc2;
        for (int d = 1; d < 32; d <<= 1) {
            int t2 = __shfl_up(incl2, d, 32);
            if (w >= d) incl2 += t2;
        }
        int ex2 = incl2 - pc2;
        pfx[wid][w] = (unsigned)ex2;
        if (w == 31) Scnt[wid] = incl2;
        u64 vv = v;
        int r = 0;
        while (vv) {
            int b = __ffsll(vv) - 1;
            vv &= vv - 1;
            members[wid][ex2 + r] = (unsigned)((w << 6) + b);   // halves write same data
            ++r;
        }
    }
    __syncthreads();
    const int S = Scnt[wid];
    const int s0 = lane, s1 = lane + 64;

    // ---- initial WL labels (argmax16, first-max tie-break), float4 loads ----
    unsigned hl0 = 0, hl1 = 0;
    if (s0 < S) {
        const float4* xr = (const float4*)(x + (size_t)members[wid][s0] * LABELS);
        float4 a0 = xr[0], a1 = xr[1], a2 = xr[2], a3 = xr[3];
        float vv[16] = {a0.x,a0.y,a0.z,a0.w,a1.x,a1.y,a1.z,a1.w,
                        a2.x,a2.y,a2.z,a2.w,a3.x,a3.y,a3.z,a3.w};
        float best = vv[0]; int bi = 0;
        #pragma unroll
        for (int c = 1; c < 16; ++c) { if (vv[c] > best) { best = vv[c]; bi = c; } }
        hl0 = mixu((unsigned)(bi + 1));
    }
    if (s1 < S) {
        const float4* xr = (const float4*)(x + (size_t)members[wid][s1] * LABELS);
        float4 a0 = xr[0], a1 = xr[1], a2 = xr[2], a3 = xr[3];
        float vv[16] = {a0.x,a0.y,a0.z,a0.w,a1.x,a1.y,a1.z,a1.w,
                        a2.x,a2.y,a2.z,a2.w,a3.x,a3.y,a3.z,a3.w};
        float best = vv[0]; int bi = 0;
        #pragma unroll
        for (int c = 1; c < 16; ++c) { if (vv[c] > best) { best = vv[c]; bi = c; } }
        hl1 = mixu((unsigned)(bi + 1));
    }
    if (s0 < S) h[wid][s0] = hl0;
    if (s1 < S) h[wid][s1] = hl1;

    // ---- compact ego adjacency (half-wave per slot, depth-2 prefetch) ----
    {
        int hw = lane >> 5, wl = lane & 31;
        u64 mw = mmask[wid][wl];
        unsigned base = pfx[wid][wl];
        u64 vcur = 0;
        if (hw < S) vcur = Adense[(size_t)members[wid][hw] * WORDS + wl] & mw;
        for (int t = hw; t < S; t += 2) {
            u64 vnext = 0;
            if (t + 2 < S) vnext = Adense[(size_t)members[wid][t + 2] * WORDS + wl] & mw;
            u64 v = vcur;
            while (v) {
                int b = __ffsll(v) - 1;
                v &= v - 1;
                int slot = (int)base + __popcll(mw & ((1ull << b) - 1));
                atomicOr(&adjs[wid][t][slot >> 5], 1u << (slot & 31));
            }
            vcur = vnext;
        }
    }
    __syncthreads();

    unsigned crossReg[FILTERS];
    #pragma unroll
    for (int f = 0; f < FILTERS; ++f) crossReg[f] = 0;
    unsigned selfeReg = 0;

    for (int t = 0; t < WL_LEVELS; ++t) {
        if (t > 0) {
            if (s0 < S) mixed[wid][s0] = mixu(h[wid][s0]);
            if (s1 < S) mixed[wid][s1] = mixu(h[wid][s1]);
            __syncthreads();
            unsigned hn0 = 0, hn1 = 0;
            if (s0 < S) {
                unsigned msg = 0;
                uint4 aw = *(const uint4*)adjs[wid][s0];
                unsigned bw[4] = {aw.x, aw.y, aw.z, aw.w};
                #pragma unroll
                for (int w = 0; w < 4; ++w) {
                    unsigned bits = bw[w];
                    while (bits) { int l = __ffs(bits) - 1; bits &= bits - 1; msg += mixed[wid][(w << 5) + l]; }
                }
                hn0 = mixu(h[wid][s0] * 0x9E3779B1u + msg);
            }
            if (s1 < S) {
                unsigned msg = 0;
                uint4 aw = *(const uint4*)adjs[wid][s1];
                unsigned bw[4] = {aw.x, aw.y, aw.z, aw.w};
                #pragma unroll
                for (int w = 0; w < 4; ++w) {
                    unsigned bits = bw[w];
                    while (bits) { int l = __ffs(bits) - 1; bits &= bits - 1; msg += mixed[wid][(w << 5) + l]; }
                }
                hn1 = mixu(h[wid][s1] * 0x9E3779B1u + msg);
            }
            __syncthreads();
            if (s0 < S) h[wid][s0] = hn0;
            if (s1 < S) h[wid][s1] = hn1;
        }
        __syncthreads();

        unsigned hv0 = (s0 < S) ? h[wid][s0] : 0u;
        unsigned hv1 = (s1 < S) ? h[wid][s1] : 0u;
        const unsigned* hrow = &hf_s[t * FILTERS * FNODES];
        if (s0 < S) {
            #pragma unroll
            for (int f = 0; f < FILTERS; ++f) {
                unsigned fm = fmb[f], c = 0;
                #pragma unroll
                for (int m = 0; m < FNODES; ++m)
                    c += (unsigned)((hv0 == hrow[f * FNODES + m]) & ((fm >> m) & 1u));
                crossReg[f] += c;
            }
        }
        if (s1 < S) {
            #pragma unroll
            for (int f = 0; f < FILTERS; ++f) {
                unsigned fm = fmb[f], c = 0;
                #pragma unroll
                for (int m = 0; m < FNODES; ++m)
                    c += (unsigned)((hv1 == hrow[f * FNODES + m]) & ((fm >> m) & 1u));
                crossReg[f] += c;
            }
        }
        {
            unsigned ce = 0;
            bool p0 = (s0 < S), p1 = (s1 < S);
            for (int l = 0; l < S; ++l) {
                unsigned hl = h[wid][l];
                ce += (unsigned)(p0 & (hl == hv0));
                ce += (unsigned)(p1 & (hl == hv1));
            }
            selfeReg += ce;
        }
        __syncthreads();
    }

    // ---- per-wave reduction (seed-local): shfl_down, lane0 -> LDS ----
    #pragma unroll
    for (int f = 0; f < FILTERS; ++f) {
        unsigned v = crossReg[f];
        for (int o = 32; o > 0; o >>= 1) v += __shfl_down(v, o, 64);
        crossReg[f] = v;
    }
    {
        unsigned v = selfeReg;
        for (int o = 32; o > 0; o >>= 1) v += __shfl_down(v, o, 64);
        selfeReg = v;
    }
    if (lane == 0) {
        #pragma unroll
        for (int f = 0; f < FILTERS; ++f) cross_sh[wid][f] = crossReg[f];
        Scnt[wid] = (int)selfeReg;   // reuse as selfe total
    }
    __syncthreads();

    if (lane < FILTERS) {
        float se = (float)Scnt[wid];
        float sf = selff[lane];
        float denom = sqrtf(se * sf);
        float v = (denom > 0.f) ? ((float)cross_sh[wid][lane] / denom) : 0.f;
        out[(size_t)i * FILTERS + lane] = v;
    }
}

extern "C" void kernel_launch(void* const* d_in, const int* in_sizes, int n_in,
                              void* d_out, int out_size, void* d_ws, size_t ws_size,
                              hipStream_t stream) {
    const float* x  = (const float*)d_in[0];
    const int*   ei = (const int*)d_in[1];
    // d_in[2] = batch (unused: single graph)
    const float* A  = (const float*)d_in[3];
    const float* X  = (const float*)d_in[4];
    float* out = (float*)d_out;
    int E2 = in_sizes[1] / 2;   // directed edge count (both directions present)

    char* ws = (char*)d_ws;
    const size_t ADJ_BYTES = (size_t)N_NODES * WORDS * sizeof(u64); // 512 KB
    u64* Adense = (u64*)(ws);
    u64* r2     = (u64*)(ws + ADJ_BYTES);
    unsigned* hf      = (unsigned*)(ws + 2 * ADJ_BYTES);
    unsigned* fmaskb  = (unsigned*)(ws + 2 * ADJ_BYTES + 4096);
    float*    selff   = (float*)  (ws + 2 * ADJ_BYTES + 4096 + 256);

    hipMemsetAsync(Adense, 0, ADJ_BYTES, stream);
    build_adj_kernel<<<(E2 + 255) / 256, 256, 0, stream>>>(ei, E2, Adense);
    // r2 = (I|A)^2 ; third hop fused into ego_kernel
    reach_step_kernel<<<N_NODES / 2, 64, 0, stream>>>(Adense, Adense, r2, 1);
    filters_kernel<<<1, 64, 0, stream>>>(A, X, hf, fmaskb, selff);
    ego_kernel<<<N_NODES / SPB, 128, 0, stream>>>(x, Adense, r2, hf, fmaskb, selff, out);
}